// Round 2
// baseline (806.106 us; speedup 1.0000x reference)
//
#include <hip/hip_runtime.h>

#define N_PTS 500000
#define FEAT 24
#define HID 168
#define OUT_C 35
#define MT 128          // points per block
#define A1_STR 40       // feat tile row stride (ushorts)
#define A2_STR 200      // h tile row stride (ushorts), rows = points, cols = hidden (192 pad + 8)

// ws layout (bf16 / ushort elements):
//   Wt1: 3 x [176][32]   at 0        (3*5632  = 16896)
//   Wt2: 3 x [176][192]  at 16896    (3*33792 = 101376)
//   Wt3: 3 x [48][192]   at 118272   (3*9216  = 27648)   -> weights total 145920
//   planes channel-last bf16: [y*S+x][8] per (scale,plane)
#define WT1_OFF 0
#define WT2_OFF 16896
#define WT3_OFF 118272
#define W_TOTAL 145920
#define PL_S0 (W_TOTAL)                    // scale0: 3 * 128*128*8 = 393216
#define PL_S1 (PL_S0 + 393216)             // scale1: 3 * 256*256*8 = 1572864
#define PL_S2 (PL_S1 + 1572864)            // scale2: 3 * 512*512*8 = 6291456
#define PL_TOTAL 8257536

typedef short bf16x8 __attribute__((ext_vector_type(8)));
typedef float f32x4 __attribute__((ext_vector_type(4)));

__device__ __forceinline__ unsigned short f2bf(float f) {
    union { float f; unsigned int u; } v; v.f = f;
    unsigned int u = v.u;
    return (unsigned short)((u + 0x7FFFu + ((u >> 16) & 1u)) >> 16);
}
__device__ __forceinline__ float bf2f(unsigned short h) {
    union { unsigned int u; float f; } v; v.u = ((unsigned int)h) << 16;
    return v.f;
}
__device__ __forceinline__ f32x4 mfma16(bf16x8 a, bf16x8 b, f32x4 c) {
    return __builtin_amdgcn_mfma_f32_16x16x32_bf16(a, b, c, 0, 0, 0);
}

__global__ __launch_bounds__(256) void prep_weights(
    const float* __restrict__ w1a, const float* __restrict__ w2a, const float* __restrict__ w3a,
    const float* __restrict__ w1b, const float* __restrict__ w2b, const float* __restrict__ w3b,
    const float* __restrict__ w1c, const float* __restrict__ w2c, const float* __restrict__ w3c,
    unsigned short* __restrict__ ws)
{
    int id = blockIdx.x * 256 + threadIdx.x;
    if (id >= W_TOTAL) return;
    const float* w1[3] = {w1a, w1b, w1c};
    const float* w2[3] = {w2a, w2b, w2c};
    const float* w3[3] = {w3a, w3b, w3c};
    float v = 0.f;
    if (id < WT2_OFF) {                       // Wt1[n][k] = w1[k][n], [176][32]
        int s = id / 5632, r = id % 5632, n = r / 32, k = r % 32;
        if (n < HID && k < FEAT) v = w1[s][k * HID + n];
    } else if (id < WT3_OFF) {                // Wt2[n][k] = w2[k][n], [176][192]
        int t = id - WT2_OFF;
        int s = t / 33792, r = t % 33792, n = r / 192, k = r % 192;
        if (n < HID && k < HID) v = w2[s][k * HID + n];
    } else {                                  // Wt3[n][k] = w3[k][n], [48][192]
        int t = id - WT3_OFF;
        int s = t / 9216, r = t % 9216, n = r / 192, k = r % 192;
        if (n < OUT_C && k < HID) v = w3[s][k * OUT_C + n];
    }
    ws[id] = f2bf(v);
}

// channel-last bf16 repack: ws[base + (y*S+x)*8 + c] = plane[c][y][x]
__global__ __launch_bounds__(256) void prep_planes(
    const float* __restrict__ xy0, const float* __restrict__ xz0, const float* __restrict__ yz0,
    const float* __restrict__ xy1, const float* __restrict__ xz1, const float* __restrict__ yz1,
    const float* __restrict__ xy2, const float* __restrict__ xz2, const float* __restrict__ yz2,
    unsigned short* __restrict__ ws)
{
    int id = blockIdx.x * 256 + threadIdx.x;
    if (id >= PL_TOTAL) return;
    const float* pls[9] = {xy0, xz0, yz0, xy1, xz1, yz1, xy2, xz2, yz2};
    int s, S2shift, r, base, pbase;
    if (id < 393216)                { s = 0; S2shift = 17; r = id;                base = PL_S0; }  // 128*128*8 = 2^17
    else if (id < 393216 + 1572864) { s = 1; S2shift = 19; r = id - 393216;      base = PL_S1; }  // 256*256*8 = 2^19
    else                            { s = 2; S2shift = 21; r = id - 1966080;     base = PL_S2; }  // 512*512*8 = 2^21
    int pl  = r >> S2shift;
    int rem = r & ((1 << S2shift) - 1);
    int pos = rem >> 3;            // y*S + x
    int c   = rem & 7;
    int SS  = 1 << (S2shift - 3);  // S*S
    float v = pls[s * 3 + pl][c * SS + pos];
    ws[base + r] = f2bf(v);
}

__global__ __launch_bounds__(512, 4) void tri_mlp(
    const float* __restrict__ xyz,
    const float* __restrict__ b1_0, const float* __restrict__ b2_0, const float* __restrict__ b3_0,
    const float* __restrict__ b1_1, const float* __restrict__ b2_1, const float* __restrict__ b3_1,
    const float* __restrict__ b1_2, const float* __restrict__ b2_2, const float* __restrict__ b3_2,
    const unsigned short* __restrict__ wpack,
    float* __restrict__ out)
{
    __shared__ __align__(16) unsigned short A1[MT * A1_STR];     // 10240 B  [point][feat k, pad 32]
    __shared__ __align__(16) unsigned short A2[MT * A2_STR];     // 51200 B  [point][hidden, pad 192]

    const int tid  = threadIdx.x;
    const int wave = tid >> 6;
    const int lane = tid & 63;
    const int quad = lane >> 4;
    const int l16  = lane & 15;
    const int p0   = blockIdx.x * MT;

    // wave partition for GEMM1/2: wn in 0..3 -> point tiles {2wn,2wn+1}; wm in 0..1 -> hidden tiles
    const int wn = wave & 3;
    const int wm = wave >> 2;
    const int m0 = wm * 6;                 // hidden tiles m0..m0+5 (wm=1: 6..10, 5 tiles)

    // zero LDS (pad cols must be 0; avoids NaN garbage in unwritten regions)
    {
        uint4 z = {0u, 0u, 0u, 0u};
        uint4* a1v = (uint4*)A1;
        uint4* a2v = (uint4*)A2;
        for (int i = tid; i < MT * A1_STR / 8; i += 512) a1v[i] = z;
        for (int i = tid; i < MT * A2_STR / 8; i += 512) a2v[i] = z;
    }

    // sampling setup (hoisted): waves 0..5 are fully active samplers
    float X = 0.f, Y = 0.f, Z = 0.f;
    int pl = 0, p = 0;
    if (tid < 384) {
        pl = tid >> 7;                     // 0=xy 1=xz 2=yz (wave-uniform: 2 waves per plane)
        p  = tid & 127;
        int gp = min(p0 + p, N_PTS - 1);
        X = xyz[gp * 3 + 0]; Y = xyz[gp * 3 + 1]; Z = xyz[gp * 3 + 2];
    }

    f32x4 c3[3];
    #pragma unroll
    for (int nt = 0; nt < 3; ++nt) c3[nt] = (f32x4){0.f, 0.f, 0.f, 0.f};

    __syncthreads();

    #pragma unroll 1
    for (int s = 0; s < 3; ++s) {
        const float *b1, *b2;
        int S, sbase;
        if (s == 0)      { b1 = b1_0; b2 = b2_0; S = 128; sbase = PL_S0; }
        else if (s == 1) { b1 = b1_1; b2 = b2_1; S = 256; sbase = PL_S1; }
        else             { b1 = b1_2; b2 = b2_2; S = 512; sbase = PL_S2; }

        // ---------- sampling: 384 plane-samples -> A1 ----------
        if (tid < 384) {
            float gx, gy;
            if (pl == 0)      { gx = Y; gy = X; }
            else if (pl == 1) { gx = Z; gy = X; }
            else              { gx = Z; gy = Y; }
            gx *= 0.5f; gy *= 0.5f;        // nrm = coord/2 for range [-2,2]
            float ix = (gx + 1.0f) * 0.5f * (float)(S - 1);
            float iy = (gy + 1.0f) * 0.5f * (float)(S - 1);
            float fx = floorf(ix), fy = floorf(iy);
            int x0 = (int)fx, y0 = (int)fy;
            float wx = ix - fx, wy = iy - fy;
            int x0c = min(max(x0, 0), S - 1);
            int x1c = min(x0 + 1, S - 1);
            int y0c = min(max(y0, 0), S - 1);
            int y1c = min(y0 + 1, S - 1);
            const unsigned short* pcl = wpack + sbase + (pl << 3) * S * S;
            uint4 q00 = *(const uint4*)&pcl[(y0c * S + x0c) * 8];
            uint4 q01 = *(const uint4*)&pcl[(y0c * S + x1c) * 8];
            uint4 q10 = *(const uint4*)&pcl[(y1c * S + x0c) * 8];
            uint4 q11 = *(const uint4*)&pcl[(y1c * S + x1c) * 8];
            float w00 = (1.f - wx) * (1.f - wy), w01 = wx * (1.f - wy);
            float w10 = (1.f - wx) * wy,         w11 = wx * wy;
            const unsigned int* u00 = (const unsigned int*)&q00;
            const unsigned int* u01 = (const unsigned int*)&q01;
            const unsigned int* u10 = (const unsigned int*)&q10;
            const unsigned int* u11 = (const unsigned int*)&q11;
            uint4 pk;
            unsigned int* po = (unsigned int*)&pk;
            #pragma unroll
            for (int h = 0; h < 4; ++h) {
                float a0 = bf2f((unsigned short)(u00[h] & 0xFFFF)) * w00
                         + bf2f((unsigned short)(u01[h] & 0xFFFF)) * w01
                         + bf2f((unsigned short)(u10[h] & 0xFFFF)) * w10
                         + bf2f((unsigned short)(u11[h] & 0xFFFF)) * w11;
                float a1 = bf2f((unsigned short)(u00[h] >> 16)) * w00
                         + bf2f((unsigned short)(u01[h] >> 16)) * w01
                         + bf2f((unsigned short)(u10[h] >> 16)) * w10
                         + bf2f((unsigned short)(u11[h] >> 16)) * w11;
                po[h] = (unsigned int)f2bf(a0) | ((unsigned int)f2bf(a1) << 16);
            }
            *reinterpret_cast<uint4*>(&A1[p * A1_STR + pl * 8]) = pk;
        }
        __syncthreads();   // A1 ready; also orders prev-scale GEMM3 A2-reads before GEMM1 A2-writes

        // ---------- GEMM1: h1^T = Wt1 @ feat^T (M=hidden, N=points) ----------
        {
            const unsigned short* w1p = wpack + WT1_OFF + s * 5632;
            bf16x8 bfeat[2];
            #pragma unroll
            for (int ni = 0; ni < 2; ++ni)
                bfeat[ni] = *(const bf16x8*)&A1[((2 * wn + ni) * 16 + l16) * A1_STR + quad * 8];
            #pragma unroll
            for (int mi = 0; mi < 6; ++mi) {
                int mt = m0 + mi;
                if (mt < 11) {
                    bf16x8 afr = *(const bf16x8*)&w1p[(mt * 16 + l16) * 32 + quad * 8];
                    int r0 = mt * 16 + quad * 4;
                    float4 bias = *(const float4*)&b1[min(r0, HID - 4)];  // clamp: rows>=HID are pad (harmless)
                    #pragma unroll
                    for (int ni = 0; ni < 2; ++ni) {
                        f32x4 c = (f32x4){0.f, 0.f, 0.f, 0.f};
                        c = mfma16(afr, bfeat[ni], c);
                        unsigned int u0 = (unsigned int)f2bf(fmaxf(c[0] + bias.x, 0.f))
                                        | ((unsigned int)f2bf(fmaxf(c[1] + bias.y, 0.f)) << 16);
                        unsigned int u1 = (unsigned int)f2bf(fmaxf(c[2] + bias.z, 0.f))
                                        | ((unsigned int)f2bf(fmaxf(c[3] + bias.w, 0.f)) << 16);
                        *reinterpret_cast<uint2*>(&A2[((2 * wn + ni) * 16 + l16) * A2_STR + r0]) =
                            make_uint2(u0, u1);
                    }
                }
            }
        }
        __syncthreads();   // h1 complete

        // ---------- GEMM2: h2^T = Wt2 @ h1^T, weights straight from global(L2) ----------
        {
            f32x4 c2[2][6];
            #pragma unroll
            for (int ni = 0; ni < 2; ++ni)
                #pragma unroll
                for (int mi = 0; mi < 6; ++mi)
                    c2[ni][mi] = (f32x4){0.f, 0.f, 0.f, 0.f};
            const unsigned short* w2p = wpack + WT2_OFF + s * 33792;
            #pragma unroll 1
            for (int kk = 0; kk < 6; ++kk) {
                bf16x8 bh[2];
                #pragma unroll
                for (int ni = 0; ni < 2; ++ni)
                    bh[ni] = *(const bf16x8*)&A2[((2 * wn + ni) * 16 + l16) * A2_STR + kk * 32 + quad * 8];
                #pragma unroll
                for (int mi = 0; mi < 6; ++mi) {
                    int mt = m0 + mi;
                    if (mt < 11) {
                        bf16x8 afr = *(const bf16x8*)&w2p[(mt * 16 + l16) * 192 + kk * 32 + quad * 8];
                        c2[0][mi] = mfma16(afr, bh[0], c2[0][mi]);
                        c2[1][mi] = mfma16(afr, bh[1], c2[1][mi]);
                    }
                }
            }
            __syncthreads();   // all h1 reads done before h2 overwrites A2
            #pragma unroll
            for (int mi = 0; mi < 6; ++mi) {
                int mt = m0 + mi;
                if (mt < 11) {
                    int r0 = mt * 16 + quad * 4;
                    float4 bias = *(const float4*)&b2[min(r0, HID - 4)];
                    #pragma unroll
                    for (int ni = 0; ni < 2; ++ni) {
                        f32x4 c = c2[ni][mi];
                        unsigned int u0 = (unsigned int)f2bf(fmaxf(c[0] + bias.x, 0.f))
                                        | ((unsigned int)f2bf(fmaxf(c[1] + bias.y, 0.f)) << 16);
                        unsigned int u1 = (unsigned int)f2bf(fmaxf(c[2] + bias.z, 0.f))
                                        | ((unsigned int)f2bf(fmaxf(c[3] + bias.w, 0.f)) << 16);
                        *reinterpret_cast<uint2*>(&A2[((2 * wn + ni) * 16 + l16) * A2_STR + r0]) =
                            make_uint2(u0, u1);
                    }
                }
            }
        }
        __syncthreads();   // h2 complete

        // ---------- GEMM3: tmp += h2 @ W3 (M=points: wave owns point-tile `wave`) ----------
        {
            const unsigned short* w3p = wpack + WT3_OFF + s * 9216;
            #pragma unroll
            for (int kk = 0; kk < 6; ++kk) {
                bf16x8 ah = *(const bf16x8*)&A2[(wave * 16 + l16) * A2_STR + kk * 32 + quad * 8];
                #pragma unroll
                for (int nt = 0; nt < 3; ++nt) {
                    bf16x8 bfr = *(const bf16x8*)&w3p[(nt * 16 + l16) * 192 + kk * 32 + quad * 8];
                    c3[nt] = mfma16(ah, bfr, c3[nt]);
                }
            }
        }
        // next iteration's sampling barrier orders GEMM3 reads vs next GEMM1 writes
    }

    // ---------- epilogue: C rows = points (tile `wave`), cols = out channels ----------
    {
        #pragma unroll
        for (int nt = 0; nt < 3; ++nt) {
            int col = nt * 16 + l16;
            if (col < OUT_C) {
                float bsum = b3_0[col] + b3_1[col] + b3_2[col];
                #pragma unroll
                for (int r = 0; r < 4; ++r) {
                    int row = p0 + wave * 16 + quad * 4 + r;
                    if (row < N_PTS) {
                        float v = c3[nt][r] + bsum;
                        if (col >= 31 && col < 34)      v = 1.0f / (1.0f + expf(-v));
                        else if (col == 34)             v *= 10.0f;
                        out[row * OUT_C + col] = v;
                    }
                }
            }
        }
    }
}

extern "C" void kernel_launch(void* const* d_in, const int* in_sizes, int n_in,
                              void* d_out, int out_size, void* d_ws, size_t ws_size,
                              hipStream_t stream) {
    (void)in_sizes; (void)n_in; (void)out_size; (void)ws_size;
    const float* xyz  = (const float*)d_in[0];
    const float* xy0  = (const float*)d_in[1];
    const float* xz0  = (const float*)d_in[2];
    const float* yz0  = (const float*)d_in[3];
    const float* w1_0 = (const float*)d_in[4];
    const float* b1_0 = (const float*)d_in[5];
    const float* w2_0 = (const float*)d_in[6];
    const float* b2_0 = (const float*)d_in[7];
    const float* w3_0 = (const float*)d_in[8];
    const float* b3_0 = (const float*)d_in[9];
    const float* xy1  = (const float*)d_in[10];
    const float* xz1  = (const float*)d_in[11];
    const float* yz1  = (const float*)d_in[12];
    const float* w1_1 = (const float*)d_in[13];
    const float* b1_1 = (const float*)d_in[14];
    const float* w2_1 = (const float*)d_in[15];
    const float* b2_1 = (const float*)d_in[16];
    const float* w3_1 = (const float*)d_in[17];
    const float* b3_1 = (const float*)d_in[18];
    const float* xy2  = (const float*)d_in[19];
    const float* xz2  = (const float*)d_in[20];
    const float* yz2  = (const float*)d_in[21];
    const float* w1_2 = (const float*)d_in[22];
    const float* b1_2 = (const float*)d_in[23];
    const float* w2_2 = (const float*)d_in[24];
    const float* b2_2 = (const float*)d_in[25];
    const float* w3_2 = (const float*)d_in[26];
    const float* b3_2 = (const float*)d_in[27];

    unsigned short* ws = (unsigned short*)d_ws;
    float* out = (float*)d_out;

    prep_weights<<<(W_TOTAL + 255) / 256, 256, 0, stream>>>(
        w1_0, w2_0, w3_0, w1_1, w2_1, w3_1, w1_2, w2_2, w3_2, ws);

    prep_planes<<<(PL_TOTAL + 255) / 256, 256, 0, stream>>>(
        xy0, xz0, yz0, xy1, xz1, yz1, xy2, xz2, yz2, ws);

    tri_mlp<<<(N_PTS + MT - 1) / MT, 512, 0, stream>>>(
        xyz,
        b1_0, b2_0, b3_0, b1_1, b2_1, b3_1, b1_2, b2_2, b3_2,
        ws, out);
}

// Round 4
// 717.372 us; speedup vs baseline: 1.1237x; 1.1237x over previous
//
#include <hip/hip_runtime.h>

#define N_PTS 500000
#define FEAT 24
#define HID 168
#define OUT_C 35
#define MT 128          // points per block (4 waves x 32 points)
#define H_STR 200       // scratch row stride (ushorts): 192 + 8 pad -> 2-way banks

// ws layout (bf16 / ushort elements):
//   Wt1: 3 x [176][32]   at 0        (3*5632  = 16896)
//   Wt2: 3 x [176][192]  at 16896    (3*33792 = 101376)
//   Wt3: 3 x [48][192]   at 118272   (3*9216  = 27648)   -> weights total 145920
//   planes channel-last bf16: [pos][8] per (scale,plane)
#define WT1_OFF 0
#define WT2_OFF 16896
#define WT3_OFF 118272
#define W_TOTAL 145920
#define PL_S0 (W_TOTAL)                    // scale0: 3 * 128*128*8 = 393216
#define PL_S1 (PL_S0 + 393216)             // scale1: 3 * 256*256*8 = 1572864
#define PL_S2 (PL_S1 + 1572864)            // scale2: 3 * 512*512*8 = 6291456

typedef short bf16x8 __attribute__((ext_vector_type(8)));
typedef float f32x4 __attribute__((ext_vector_type(4)));

__device__ __forceinline__ unsigned short f2bf(float f) {
    union { float f; unsigned int u; } v; v.f = f;
    unsigned int u = v.u;
    return (unsigned short)((u + 0x7FFFu + ((u >> 16) & 1u)) >> 16);
}
__device__ __forceinline__ float bf2f(unsigned short h) {
    union { unsigned int u; float f; } v; v.u = ((unsigned int)h) << 16;
    return v.f;
}
__device__ __forceinline__ f32x4 mfma16(bf16x8 a, bf16x8 b, f32x4 c) {
    return __builtin_amdgcn_mfma_f32_16x16x32_bf16(a, b, c, 0, 0, 0);
}

__global__ __launch_bounds__(256) void prep_weights(
    const float* __restrict__ w1a, const float* __restrict__ w2a, const float* __restrict__ w3a,
    const float* __restrict__ w1b, const float* __restrict__ w2b, const float* __restrict__ w3b,
    const float* __restrict__ w1c, const float* __restrict__ w2c, const float* __restrict__ w3c,
    unsigned short* __restrict__ ws)
{
    int id = blockIdx.x * 256 + threadIdx.x;
    if (id >= W_TOTAL) return;
    const float* w1[3] = {w1a, w1b, w1c};
    const float* w2[3] = {w2a, w2b, w2c};
    const float* w3[3] = {w3a, w3b, w3c};
    float v = 0.f;
    if (id < WT2_OFF) {                       // Wt1[n][k] = w1[k][n], [176][32]
        int s = id / 5632, r = id % 5632, n = r / 32, k = r % 32;
        if (n < HID && k < FEAT) v = w1[s][k * HID + n];
    } else if (id < WT3_OFF) {                // Wt2[n][k] = w2[k][n], [176][192]
        int t = id - WT2_OFF;
        int s = t / 33792, r = t % 33792, n = r / 192, k = r % 192;
        if (n < HID && k < HID) v = w2[s][k * HID + n];
    } else {                                  // Wt3[n][k] = w3[k][n], [48][192]
        int t = id - WT3_OFF;
        int s = t / 9216, r = t % 9216, n = r / 192, k = r % 192;
        if (n < OUT_C && k < HID) v = w3[s][k * OUT_C + n];
    }
    ws[id] = f2bf(v);
}

// channel-last bf16 repack, coalesced both sides.
__global__ __launch_bounds__(256) void prep_planes(
    const float* __restrict__ xy0, const float* __restrict__ xz0, const float* __restrict__ yz0,
    const float* __restrict__ xy1, const float* __restrict__ xz1, const float* __restrict__ yz1,
    const float* __restrict__ xy2, const float* __restrict__ xz2, const float* __restrict__ yz2,
    unsigned short* __restrict__ ws)
{
    const float* pls[9] = {xy0, xz0, yz0, xy1, xz1, yz1, xy2, xz2, yz2};
    int b = blockIdx.x;
    int s, pl, chunk, SS, base;
    if (b < 192)        { s = 0; SS = 16384;  pl = b / 64;   chunk = b % 64;    base = PL_S0; }
    else if (b < 960)   { int t = b - 192; s = 1; SS = 65536;  pl = t / 256;  chunk = t % 256;  base = PL_S1; }
    else                { int t = b - 960; s = 2; SS = 262144; pl = t / 1024; chunk = t % 1024; base = PL_S2; }
    const float* src = pls[s * 3 + pl];
    int pos = chunk * 256 + threadIdx.x;
    uint4 pk;
    unsigned int* po = (unsigned int*)&pk;
    #pragma unroll
    for (int c = 0; c < 4; ++c) {
        float f0 = src[(2 * c)     * SS + pos];
        float f1 = src[(2 * c + 1) * SS + pos];
        po[c] = (unsigned int)f2bf(f0) | ((unsigned int)f2bf(f1) << 16);
    }
    *reinterpret_cast<uint4*>(&ws[base + pl * SS * 8 + pos * 8]) = pk;
}

// Fully wave-autonomous: zero __syncthreads. Wave owns 32 points (2 n-tiles).
// Sampled features land directly in B-fragment layout; h1/h2 round-trip
// through wave-private LDS scratch (intra-wave lgkmcnt ordering only).
__global__ __launch_bounds__(256, 3) void tri_mlp(
    const float* __restrict__ xyz,
    const float* __restrict__ b1_0, const float* __restrict__ b2_0, const float* __restrict__ b3_0,
    const float* __restrict__ b1_1, const float* __restrict__ b2_1, const float* __restrict__ b3_1,
    const float* __restrict__ b1_2, const float* __restrict__ b2_2, const float* __restrict__ b3_2,
    const unsigned short* __restrict__ wpack,
    float* __restrict__ out)
{
    __shared__ __align__(16) unsigned short H[MT * H_STR];   // 51200 B, wave-private slices

    const int tid  = threadIdx.x;
    const int wave = tid >> 6;
    const int lane = tid & 63;
    const int quad = lane >> 4;
    const int l16  = lane & 15;
    const int p0   = blockIdx.x * MT;
    const int prow = wave * 32;              // this wave's first point row in H

    // zero this wave's H slice (pad cols 176..191 are read as MFMA K but never
    // written -> must be 0, not stale LDS garbage). Wave-private: no barrier.
    {
        uint4 z = {0u, 0u, 0u, 0u};
        uint4* hv = (uint4*)&H[prow * H_STR];
        for (int i = lane; i < 32 * H_STR / 8; i += 64) hv[i] = z;
    }

    f32x4 c3[2][3];
    #pragma unroll
    for (int ni = 0; ni < 2; ++ni)
        #pragma unroll
        for (int mt = 0; mt < 3; ++mt)
            c3[ni][mt] = (f32x4){0.f, 0.f, 0.f, 0.f};

    #pragma unroll 1
    for (int s = 0; s < 3; ++s) {
        const float *b1, *b2;
        int S, sbase;
        if (s == 0)      { b1 = b1_0; b2 = b2_0; S = 128; sbase = PL_S0; }
        else if (s == 1) { b1 = b1_1; b2 = b2_1; S = 256; sbase = PL_S1; }
        else             { b1 = b1_2; b2 = b2_2; S = 512; sbase = PL_S2; }

        // ---------- sampling -> B1 fragments (registers, no LDS) ----------
        // lane (quad,l16): plane=quad (quad 3 -> zero pad k=24..31), point l16 (+16*ni)
        bf16x8 B1[2];
        #pragma unroll
        for (int ni = 0; ni < 2; ++ni) {
            int gp = min(p0 + prow + ni * 16 + l16, N_PTS - 1);
            uint4 pk = {0u, 0u, 0u, 0u};
            if (quad < 3) {
                float X = xyz[gp * 3 + 0], Y = xyz[gp * 3 + 1], Z = xyz[gp * 3 + 2];
                float gx, gy;
                if (quad == 0)      { gx = Y; gy = X; }
                else if (quad == 1) { gx = Z; gy = X; }
                else                { gx = Z; gy = Y; }
                gx *= 0.5f; gy *= 0.5f;      // nrm = coord/2 for range [-2,2]
                float ix = (gx + 1.0f) * 0.5f * (float)(S - 1);
                float iy = (gy + 1.0f) * 0.5f * (float)(S - 1);
                float fx = floorf(ix), fy = floorf(iy);
                int x0 = (int)fx, y0 = (int)fy;
                float wx = ix - fx, wy = iy - fy;
                int x0c = min(max(x0, 0), S - 1);
                int x1c = min(x0 + 1, S - 1);
                int y0c = min(max(y0, 0), S - 1);
                int y1c = min(y0 + 1, S - 1);
                const unsigned short* pcl = wpack + sbase + (quad << 3) * S * S;
                uint4 q00 = *(const uint4*)&pcl[(y0c * S + x0c) * 8];
                uint4 q01 = *(const uint4*)&pcl[(y0c * S + x1c) * 8];
                uint4 q10 = *(const uint4*)&pcl[(y1c * S + x0c) * 8];
                uint4 q11 = *(const uint4*)&pcl[(y1c * S + x1c) * 8];
                float w00 = (1.f - wx) * (1.f - wy), w01 = wx * (1.f - wy);
                float w10 = (1.f - wx) * wy,         w11 = wx * wy;
                const unsigned int* u00 = (const unsigned int*)&q00;
                const unsigned int* u01 = (const unsigned int*)&q01;
                const unsigned int* u10 = (const unsigned int*)&q10;
                const unsigned int* u11 = (const unsigned int*)&q11;
                unsigned int* po = (unsigned int*)&pk;
                #pragma unroll
                for (int h = 0; h < 4; ++h) {
                    float a0 = bf2f((unsigned short)(u00[h] & 0xFFFF)) * w00
                             + bf2f((unsigned short)(u01[h] & 0xFFFF)) * w01
                             + bf2f((unsigned short)(u10[h] & 0xFFFF)) * w10
                             + bf2f((unsigned short)(u11[h] & 0xFFFF)) * w11;
                    float a1 = bf2f((unsigned short)(u00[h] >> 16)) * w00
                             + bf2f((unsigned short)(u01[h] >> 16)) * w01
                             + bf2f((unsigned short)(u10[h] >> 16)) * w10
                             + bf2f((unsigned short)(u11[h] >> 16)) * w11;
                    po[h] = (unsigned int)f2bf(a0) | ((unsigned int)f2bf(a1) << 16);
                }
            }
            B1[ni] = *reinterpret_cast<bf16x8*>(&pk);
        }

        // ---------- GEMM1: h1^T = Wt1 @ feat^T -> wave-private scratch ----------
        {
            const unsigned short* w1p = wpack + WT1_OFF + s * 5632;
            #pragma unroll
            for (int mt = 0; mt < 11; ++mt) {
                bf16x8 a = *(const bf16x8*)&w1p[(mt * 16 + l16) * 32 + quad * 8];
                float4 bias = *(const float4*)&b1[min(mt * 16 + quad * 4, HID - 4)];
                #pragma unroll
                for (int ni = 0; ni < 2; ++ni) {
                    f32x4 c = (f32x4){0.f, 0.f, 0.f, 0.f};
                    c = mfma16(a, B1[ni], c);
                    unsigned int u0 = (unsigned int)f2bf(fmaxf(c[0] + bias.x, 0.f))
                                    | ((unsigned int)f2bf(fmaxf(c[1] + bias.y, 0.f)) << 16);
                    unsigned int u1 = (unsigned int)f2bf(fmaxf(c[2] + bias.z, 0.f))
                                    | ((unsigned int)f2bf(fmaxf(c[3] + bias.w, 0.f)) << 16);
                    *reinterpret_cast<uint2*>(&H[(prow + ni * 16 + l16) * H_STR + mt * 16 + quad * 4]) =
                        make_uint2(u0, u1);
                }
            }
        }

        // ---------- read h1 back as B fragments (wave-private, no barrier) ----------
        bf16x8 B2[2][6];
        #pragma unroll
        for (int ni = 0; ni < 2; ++ni)
            #pragma unroll
            for (int kk = 0; kk < 6; ++kk)
                B2[ni][kk] = *(const bf16x8*)&H[(prow + ni * 16 + l16) * H_STR + kk * 32 + quad * 8];

        // ---------- GEMM2: h2^T = Wt2 @ h1^T (mt outer, tiny C footprint) ----------
        {
            const unsigned short* w2p = wpack + WT2_OFF + s * 33792;
            #pragma unroll 2
            for (int mt = 0; mt < 11; ++mt) {
                f32x4 c2[2];
                c2[0] = (f32x4){0.f, 0.f, 0.f, 0.f};
                c2[1] = (f32x4){0.f, 0.f, 0.f, 0.f};
                #pragma unroll
                for (int kk = 0; kk < 6; ++kk) {
                    bf16x8 a = *(const bf16x8*)&w2p[(mt * 16 + l16) * 192 + kk * 32 + quad * 8];
                    c2[0] = mfma16(a, B2[0][kk], c2[0]);
                    c2[1] = mfma16(a, B2[1][kk], c2[1]);
                }
                float4 bias = *(const float4*)&b2[min(mt * 16 + quad * 4, HID - 4)];
                #pragma unroll
                for (int ni = 0; ni < 2; ++ni) {
                    unsigned int u0 = (unsigned int)f2bf(fmaxf(c2[ni][0] + bias.x, 0.f))
                                    | ((unsigned int)f2bf(fmaxf(c2[ni][1] + bias.y, 0.f)) << 16);
                    unsigned int u1 = (unsigned int)f2bf(fmaxf(c2[ni][2] + bias.z, 0.f))
                                    | ((unsigned int)f2bf(fmaxf(c2[ni][3] + bias.w, 0.f)) << 16);
                    *reinterpret_cast<uint2*>(&H[(prow + ni * 16 + l16) * H_STR + mt * 16 + quad * 4]) =
                        make_uint2(u0, u1);
                }
            }
        }

        // ---------- read h2 back as B fragments ----------
        bf16x8 B3[2][6];
        #pragma unroll
        for (int ni = 0; ni < 2; ++ni)
            #pragma unroll
            for (int kk = 0; kk < 6; ++kk)
                B3[ni][kk] = *(const bf16x8*)&H[(prow + ni * 16 + l16) * H_STR + kk * 32 + quad * 8];

        // ---------- GEMM3: tmp^T += Wt3 @ h2^T (accumulate across scales) ----------
        {
            const unsigned short* w3p = wpack + WT3_OFF + s * 9216;
            #pragma unroll
            for (int mt = 0; mt < 3; ++mt) {
                #pragma unroll
                for (int kk = 0; kk < 6; ++kk) {
                    bf16x8 a = *(const bf16x8*)&w3p[(mt * 16 + l16) * 192 + kk * 32 + quad * 8];
                    c3[0][mt] = mfma16(a, B3[0][kk], c3[0][mt]);
                    c3[1][mt] = mfma16(a, B3[1][kk], c3[1][mt]);
                }
            }
        }
    }

    // ---------- epilogue: rows = out channels, cols = points ----------
    #pragma unroll
    for (int ni = 0; ni < 2; ++ni) {
        int p = p0 + prow + ni * 16 + l16;
        if (p < N_PTS) {
            #pragma unroll
            for (int mt = 0; mt < 3; ++mt) {
                int ch0 = mt * 16 + quad * 4;
                #pragma unroll
                for (int r = 0; r < 4; ++r) {
                    int ch = ch0 + r;
                    if (ch < OUT_C) {
                        float v = c3[ni][mt][r] + b3_0[ch] + b3_1[ch] + b3_2[ch];
                        if (ch >= 31 && ch < 34)      v = 1.0f / (1.0f + expf(-v));
                        else if (ch == 34)            v *= 10.0f;
                        out[p * OUT_C + ch] = v;
                    }
                }
            }
        }
    }
}

extern "C" void kernel_launch(void* const* d_in, const int* in_sizes, int n_in,
                              void* d_out, int out_size, void* d_ws, size_t ws_size,
                              hipStream_t stream) {
    (void)in_sizes; (void)n_in; (void)out_size; (void)ws_size;
    const float* xyz  = (const float*)d_in[0];
    const float* xy0  = (const float*)d_in[1];
    const float* xz0  = (const float*)d_in[2];
    const float* yz0  = (const float*)d_in[3];
    const float* w1_0 = (const float*)d_in[4];
    const float* b1_0 = (const float*)d_in[5];
    const float* w2_0 = (const float*)d_in[6];
    const float* b2_0 = (const float*)d_in[7];
    const float* w3_0 = (const float*)d_in[8];
    const float* b3_0 = (const float*)d_in[9];
    const float* xy1  = (const float*)d_in[10];
    const float* xz1  = (const float*)d_in[11];
    const float* yz1  = (const float*)d_in[12];
    const float* w1_1 = (const float*)d_in[13];
    const float* b1_1 = (const float*)d_in[14];
    const float* w2_1 = (const float*)d_in[15];
    const float* b2_1 = (const float*)d_in[16];
    const float* w3_1 = (const float*)d_in[17];
    const float* b3_1 = (const float*)d_in[18];
    const float* xy2  = (const float*)d_in[19];
    const float* xz2  = (const float*)d_in[20];
    const float* yz2  = (const float*)d_in[21];
    const float* w1_2 = (const float*)d_in[22];
    const float* b1_2 = (const float*)d_in[23];
    const float* w2_2 = (const float*)d_in[24];
    const float* b2_2 = (const float*)d_in[25];
    const float* w3_2 = (const float*)d_in[26];
    const float* b3_2 = (const float*)d_in[27];

    unsigned short* ws = (unsigned short*)d_ws;
    float* out = (float*)d_out;

    prep_weights<<<(W_TOTAL + 255) / 256, 256, 0, stream>>>(
        w1_0, w2_0, w3_0, w1_1, w2_1, w3_1, w1_2, w2_2, w3_2, ws);

    prep_planes<<<4032, 256, 0, stream>>>(
        xy0, xz0, yz0, xy1, xz1, yz1, xy2, xz2, yz2, ws);

    tri_mlp<<<(N_PTS + MT - 1) / MT, 256, 0, stream>>>(
        xyz,
        b1_0, b2_0, b3_0, b1_1, b2_1, b3_1, b1_2, b2_2, b3_2,
        ws, out);
}

// Round 6
// 635.222 us; speedup vs baseline: 1.2690x; 1.1293x over previous
//
#include <hip/hip_runtime.h>

#define N_PTS 500000
#define FEAT 24
#define HID 168
#define OUT_C 35
#define MT 128          // points per block (4 waves x 32 points)
#define H_STR 200       // scratch row stride (ushorts): 192 + 8 pad

// ws layout (ushort elements), all weights in MFMA fragment-major order:
//   W1frag: [s][mt(12)][lane(64)][8]        at 0       (3*6144  = 18432)
//   W2frag: [s][kk(6)][mt(12)][lane][8]     at 18432   (3*36864 = 110592)
//   W3frag: [s][mt(3)][kk(6)][lane][8]      at 129024  (3*9216  = 27648)
#define WF1_OFF 0
#define WF2_OFF 18432
#define WF3_OFF 129024
#define W_TOTAL 156672
#define PL_S0 (W_TOTAL)                    // scale0: 3 * 128*128*8 = 393216
#define PL_S1 (PL_S0 + 393216)             // scale1: 3 * 256*256*8 = 1572864
#define PL_S2 (PL_S1 + 1572864)            // scale2: 3 * 512*512*8 = 6291456

typedef short bf16x8 __attribute__((ext_vector_type(8)));
typedef float f32x4 __attribute__((ext_vector_type(4)));

__device__ __forceinline__ unsigned short f2bf(float f) {
    union { float f; unsigned int u; } v; v.f = f;
    unsigned int u = v.u;
    return (unsigned short)((u + 0x7FFFu + ((u >> 16) & 1u)) >> 16);
}
__device__ __forceinline__ float bf2f(unsigned short h) {
    union { unsigned int u; float f; } v; v.u = ((unsigned int)h) << 16;
    return v.f;
}
__device__ __forceinline__ unsigned int pk_bf16(float a, float b) {
    return (unsigned int)f2bf(a) | ((unsigned int)f2bf(b) << 16);
}
__device__ __forceinline__ f32x4 mfma16(bf16x8 a, bf16x8 b, f32x4 c) {
    return __builtin_amdgcn_mfma_f32_16x16x32_bf16(a, b, c, 0, 0, 0);
}

__global__ __launch_bounds__(256) void prep_weights(
    const float* __restrict__ w1a, const float* __restrict__ w2a, const float* __restrict__ w3a,
    const float* __restrict__ w1b, const float* __restrict__ w2b, const float* __restrict__ w3b,
    const float* __restrict__ w1c, const float* __restrict__ w2c, const float* __restrict__ w3c,
    unsigned short* __restrict__ ws)
{
    int id = blockIdx.x * 256 + threadIdx.x;
    if (id >= W_TOTAL) return;
    const float* w1[3] = {w1a, w1b, w1c};
    const float* w2[3] = {w2a, w2b, w2c};
    const float* w3[3] = {w3a, w3b, w3c};
    float v = 0.f;
    if (id < WF2_OFF) {                       // W1frag [s][mt][lane][8]
        int s = id / 6144, r = id % 6144;
        int mt = r >> 9, q = r & 511, lane = q >> 3, j = q & 7;
        int n = mt * 16 + (lane & 15), k = (lane >> 4) * 8 + j;
        if (n < HID && k < FEAT) v = w1[s][k * HID + n];
    } else if (id < WF3_OFF) {                // W2frag [s][kk][mt][lane][8]
        int t = id - WF2_OFF;
        int s = t / 36864, r = t % 36864;
        int fi = r >> 9, q = r & 511, lane = q >> 3, j = q & 7;
        int kk = fi / 12, mt = fi % 12;
        int n = mt * 16 + (lane & 15), k = kk * 32 + (lane >> 4) * 8 + j;
        if (n < HID && k < HID) v = w2[s][k * HID + n];
    } else {                                  // W3frag [s][mt][kk][lane][8]
        int t = id - WF3_OFF;
        int s = t / 9216, r = t % 9216;
        int fi = r >> 9, q = r & 511, lane = q >> 3, j = q & 7;
        int mt = fi / 6, kk = fi % 6;
        int n = mt * 16 + (lane & 15), k = kk * 32 + (lane >> 4) * 8 + j;
        if (n < OUT_C && k < HID) v = w3[s][k * OUT_C + n];
    }
    ws[id] = f2bf(v);
}

// channel-last bf16 repack, coalesced both sides.
__global__ __launch_bounds__(256) void prep_planes(
    const float* __restrict__ xy0, const float* __restrict__ xz0, const float* __restrict__ yz0,
    const float* __restrict__ xy1, const float* __restrict__ xz1, const float* __restrict__ yz1,
    const float* __restrict__ xy2, const float* __restrict__ xz2, const float* __restrict__ yz2,
    unsigned short* __restrict__ ws)
{
    const float* pls[9] = {xy0, xz0, yz0, xy1, xz1, yz1, xy2, xz2, yz2};
    int b = blockIdx.x;
    int s, pl, chunk, SS, base;
    if (b < 192)        { s = 0; SS = 16384;  pl = b / 64;   chunk = b % 64;    base = PL_S0; }
    else if (b < 960)   { int t = b - 192; s = 1; SS = 65536;  pl = t / 256;  chunk = t % 256;  base = PL_S1; }
    else                { int t = b - 960; s = 2; SS = 262144; pl = t / 1024; chunk = t % 1024; base = PL_S2; }
    const float* src = pls[s * 3 + pl];
    int pos = chunk * 256 + threadIdx.x;
    uint4 pk;
    unsigned int* po = (unsigned int*)&pk;
    #pragma unroll
    for (int c = 0; c < 4; ++c) {
        float f0 = src[(2 * c)     * SS + pos];
        float f1 = src[(2 * c + 1) * SS + pos];
        po[c] = pk_bf16(f0, f1);
    }
    *reinterpret_cast<uint4*>(&ws[base + pl * SS * 8 + pos * 8]) = pk;
}

// Wave-autonomous (zero __syncthreads). Wave owns 32 points (2 n-tiles).
// All weight loads are fragment-major coalesced dwordx4 at base + lane*16.
__global__ __launch_bounds__(256, 3) void tri_mlp(
    const float* __restrict__ xyz,
    const float* __restrict__ b1_0, const float* __restrict__ b2_0, const float* __restrict__ b3_0,
    const float* __restrict__ b1_1, const float* __restrict__ b2_1, const float* __restrict__ b3_1,
    const float* __restrict__ b1_2, const float* __restrict__ b2_2, const float* __restrict__ b3_2,
    const unsigned short* __restrict__ wpack,
    float* __restrict__ out)
{
    __shared__ __align__(16) unsigned short H[MT * H_STR];   // 51200 B, wave-private slices

    const int tid  = threadIdx.x;
    const int wave = tid >> 6;
    const int lane = tid & 63;
    const int quad = lane >> 4;
    const int l16  = lane & 15;
    const int p0   = blockIdx.x * MT;
    const int prow = wave * 32;              // this wave's first point row in H

    // c3 pre-loaded with summed bias (accumulates across scales)
    f32x4 c3[2][3];
    #pragma unroll
    for (int mt = 0; mt < 3; ++mt) {
        f32x4 cb;
        #pragma unroll
        for (int r = 0; r < 4; ++r) {
            int ch = mt * 16 + quad * 4 + r;
            cb[r] = (ch < OUT_C) ? (b3_0[ch] + b3_1[ch] + b3_2[ch]) : 0.f;
        }
        c3[0][mt] = cb;
        c3[1][mt] = cb;
    }

    #pragma unroll 1
    for (int s = 0; s < 3; ++s) {
        const float *b1, *b2;
        int S, sbase;
        if (s == 0)      { b1 = b1_0; b2 = b2_0; S = 128; sbase = PL_S0; }
        else if (s == 1) { b1 = b1_1; b2 = b2_1; S = 256; sbase = PL_S1; }
        else             { b1 = b1_2; b2 = b2_2; S = 512; sbase = PL_S2; }

        // ---------- sampling -> B1 fragments (registers) ----------
        // lane (quad,l16): plane=quad (quad 3 -> zero pad k=24..31), point l16 (+16*ni)
        bf16x8 B1[2];
        #pragma unroll
        for (int ni = 0; ni < 2; ++ni) {
            int gp = min(p0 + prow + ni * 16 + l16, N_PTS - 1);
            uint4 pk = {0u, 0u, 0u, 0u};
            if (quad < 3) {
                float X = xyz[gp * 3 + 0], Y = xyz[gp * 3 + 1], Z = xyz[gp * 3 + 2];
                float gx, gy;
                if (quad == 0)      { gx = Y; gy = X; }
                else if (quad == 1) { gx = Z; gy = X; }
                else                { gx = Z; gy = Y; }
                gx *= 0.5f; gy *= 0.5f;      // nrm = coord/2 for range [-2,2]
                float ix = (gx + 1.0f) * 0.5f * (float)(S - 1);
                float iy = (gy + 1.0f) * 0.5f * (float)(S - 1);
                float fx = floorf(ix), fy = floorf(iy);
                int x0 = (int)fx, y0 = (int)fy;
                float wx = ix - fx, wy = iy - fy;
                int x0c = min(max(x0, 0), S - 1);
                int x1c = min(x0 + 1, S - 1);
                int y0c = min(max(y0, 0), S - 1);
                int y1c = min(y0 + 1, S - 1);
                const unsigned short* pcl = wpack + sbase + (quad << 3) * S * S;
                uint4 q00 = *(const uint4*)&pcl[(y0c * S + x0c) * 8];
                uint4 q01 = *(const uint4*)&pcl[(y0c * S + x1c) * 8];
                uint4 q10 = *(const uint4*)&pcl[(y1c * S + x0c) * 8];
                uint4 q11 = *(const uint4*)&pcl[(y1c * S + x1c) * 8];
                float w00 = (1.f - wx) * (1.f - wy), w01 = wx * (1.f - wy);
                float w10 = (1.f - wx) * wy,         w11 = wx * wy;
                const unsigned int* u00 = (const unsigned int*)&q00;
                const unsigned int* u01 = (const unsigned int*)&q01;
                const unsigned int* u10 = (const unsigned int*)&q10;
                const unsigned int* u11 = (const unsigned int*)&q11;
                unsigned int* po = (unsigned int*)&pk;
                #pragma unroll
                for (int h = 0; h < 4; ++h) {
                    float a0 = bf2f((unsigned short)(u00[h] & 0xFFFF)) * w00
                             + bf2f((unsigned short)(u01[h] & 0xFFFF)) * w01
                             + bf2f((unsigned short)(u10[h] & 0xFFFF)) * w10
                             + bf2f((unsigned short)(u11[h] & 0xFFFF)) * w11;
                    float a1 = bf2f((unsigned short)(u00[h] >> 16)) * w00
                             + bf2f((unsigned short)(u01[h] >> 16)) * w01
                             + bf2f((unsigned short)(u10[h] >> 16)) * w10
                             + bf2f((unsigned short)(u11[h] >> 16)) * w11;
                    po[h] = pk_bf16(a0, a1);
                }
            }
            B1[ni] = *reinterpret_cast<bf16x8*>(&pk);
        }

        // ---------- GEMM1: h1^T = Wt1 @ feat^T -> wave-private H ----------
        {
            const unsigned short* w1f = wpack + WF1_OFF + s * 6144;
            #pragma unroll
            for (int mt = 0; mt < 12; ++mt) {
                bf16x8 a = *(const bf16x8*)&w1f[mt * 512 + lane * 8];
                float4 bias = *(const float4*)&b1[min(mt * 16 + quad * 4, HID - 4)];
                f32x4 cb = {bias.x, bias.y, bias.z, bias.w};
                #pragma unroll
                for (int ni = 0; ni < 2; ++ni) {
                    f32x4 c = mfma16(a, B1[ni], cb);
                    unsigned int u0 = pk_bf16(fmaxf(c[0], 0.f), fmaxf(c[1], 0.f));
                    unsigned int u1 = pk_bf16(fmaxf(c[2], 0.f), fmaxf(c[3], 0.f));
                    *reinterpret_cast<uint2*>(&H[(prow + ni * 16 + l16) * H_STR + mt * 16 + quad * 4]) =
                        make_uint2(u0, u1);
                }
            }
        }

        // ---------- read h1 back as B fragments (wave-private) ----------
        bf16x8 B2[2][6];
        #pragma unroll
        for (int ni = 0; ni < 2; ++ni)
            #pragma unroll
            for (int kk = 0; kk < 6; ++kk)
                B2[ni][kk] = *(const bf16x8*)&H[(prow + ni * 16 + l16) * H_STR + kk * 32 + quad * 8];

        // ---------- GEMM2: kk-outer, two mt-halves of 6 tiles ----------
        {
            const unsigned short* w2f = wpack + WF2_OFF + s * 36864;
            #pragma unroll 1
            for (int hh = 0; hh < 2; ++hh) {
                const int mtb = hh * 6;
                f32x4 c2[6][2];
                #pragma unroll
                for (int mi = 0; mi < 6; ++mi) {
                    float4 bias = *(const float4*)&b2[min((mtb + mi) * 16 + quad * 4, HID - 4)];
                    c2[mi][0] = (f32x4){bias.x, bias.y, bias.z, bias.w};
                    c2[mi][1] = c2[mi][0];
                }
                #pragma unroll 2
                for (int kk = 0; kk < 6; ++kk) {
                    #pragma unroll
                    for (int mi = 0; mi < 6; ++mi) {
                        bf16x8 a = *(const bf16x8*)&w2f[(kk * 12 + mtb + mi) * 512 + lane * 8];
                        c2[mi][0] = mfma16(a, B2[0][kk], c2[mi][0]);
                        c2[mi][1] = mfma16(a, B2[1][kk], c2[mi][1]);
                    }
                }
                #pragma unroll
                for (int mi = 0; mi < 6; ++mi) {
                    #pragma unroll
                    for (int ni = 0; ni < 2; ++ni) {
                        f32x4 c = c2[mi][ni];
                        unsigned int u0 = pk_bf16(fmaxf(c[0], 0.f), fmaxf(c[1], 0.f));
                        unsigned int u1 = pk_bf16(fmaxf(c[2], 0.f), fmaxf(c[3], 0.f));
                        *reinterpret_cast<uint2*>(
                            &H[(prow + ni * 16 + l16) * H_STR + (mtb + mi) * 16 + quad * 4]) =
                            make_uint2(u0, u1);
                    }
                }
            }
        }

        // ---------- read h2 back as B fragments ----------
        bf16x8 B3[2][6];
        #pragma unroll
        for (int ni = 0; ni < 2; ++ni)
            #pragma unroll
            for (int kk = 0; kk < 6; ++kk)
                B3[ni][kk] = *(const bf16x8*)&H[(prow + ni * 16 + l16) * H_STR + kk * 32 + quad * 8];

        // ---------- GEMM3: tmp^T += Wt3 @ h2^T ----------
        {
            const unsigned short* w3f = wpack + WF3_OFF + s * 9216;
            #pragma unroll
            for (int mt = 0; mt < 3; ++mt) {
                #pragma unroll
                for (int kk = 0; kk < 6; ++kk) {
                    bf16x8 a = *(const bf16x8*)&w3f[(mt * 6 + kk) * 512 + lane * 8];
                    c3[0][mt] = mfma16(a, B3[0][kk], c3[0][mt]);
                    c3[1][mt] = mfma16(a, B3[1][kk], c3[1][mt]);
                }
            }
        }
    }

    // ---------- epilogue (bias already in c3) ----------
    #pragma unroll
    for (int ni = 0; ni < 2; ++ni) {
        int p = p0 + prow + ni * 16 + l16;
        if (p < N_PTS) {
            #pragma unroll
            for (int mt = 0; mt < 3; ++mt) {
                int ch0 = mt * 16 + quad * 4;
                #pragma unroll
                for (int r = 0; r < 4; ++r) {
                    int ch = ch0 + r;
                    if (ch < OUT_C) {
                        float v = c3[ni][mt][r];
                        if (ch >= 31 && ch < 34)      v = 1.0f / (1.0f + expf(-v));
                        else if (ch == 34)            v *= 10.0f;
                        out[p * OUT_C + ch] = v;
                    }
                }
            }
        }
    }
}

extern "C" void kernel_launch(void* const* d_in, const int* in_sizes, int n_in,
                              void* d_out, int out_size, void* d_ws, size_t ws_size,
                              hipStream_t stream) {
    (void)in_sizes; (void)n_in; (void)out_size; (void)ws_size;
    const float* xyz  = (const float*)d_in[0];
    const float* xy0  = (const float*)d_in[1];
    const float* xz0  = (const float*)d_in[2];
    const float* yz0  = (const float*)d_in[3];
    const float* w1_0 = (const float*)d_in[4];
    const float* b1_0 = (const float*)d_in[5];
    const float* w2_0 = (const float*)d_in[6];
    const float* b2_0 = (const float*)d_in[7];
    const float* w3_0 = (const float*)d_in[8];
    const float* b3_0 = (const float*)d_in[9];
    const float* xy1  = (const float*)d_in[10];
    const float* xz1  = (const float*)d_in[11];
    const float* yz1  = (const float*)d_in[12];
    const float* w1_1 = (const float*)d_in[13];
    const float* b1_1 = (const float*)d_in[14];
    const float* w2_1 = (const float*)d_in[15];
    const float* b2_1 = (const float*)d_in[16];
    const float* w3_1 = (const float*)d_in[17];
    const float* b3_1 = (const float*)d_in[18];
    const float* xy2  = (const float*)d_in[19];
    const float* xz2  = (const float*)d_in[20];
    const float* yz2  = (const float*)d_in[21];
    const float* w1_2 = (const float*)d_in[22];
    const float* b1_2 = (const float*)d_in[23];
    const float* w2_2 = (const float*)d_in[24];
    const float* b2_2 = (const float*)d_in[25];
    const float* w3_2 = (const float*)d_in[26];
    const float* b3_2 = (const float*)d_in[27];

    unsigned short* ws = (unsigned short*)d_ws;
    float* out = (float*)d_out;

    prep_weights<<<(W_TOTAL + 255) / 256, 256, 0, stream>>>(
        w1_0, w2_0, w3_0, w1_1, w2_1, w3_1, w1_2, w2_2, w3_2, ws);

    prep_planes<<<4032, 256, 0, stream>>>(
        xy0, xz0, yz0, xy1, xz1, yz1, xy2, xz2, yz2, ws);

    tri_mlp<<<(N_PTS + MT - 1) / MT, 256, 0, stream>>>(
        xyz,
        b1_0, b2_0, b3_0, b1_1, b2_1, b3_1, b1_2, b2_2, b3_2,
        ws, out);
}